// Round 1
// baseline (273.521 us; speedup 1.0000x reference)
//
#include <hip/hip_runtime.h>
#include <math.h>

// Problem dims (fixed by reference)
#define NB 8
#define NC 3
#define NH 1024
#define NW 1024
#define KRAD 5      // 11x11 box, radius 5
#define KSZ 11
#define EPS 1e-6f

// Tiling
#define TH 32
#define TW 64
#define HALO_H (TH + 2 * KRAD)   // 42
#define HALO_W (TW + 2 * KRAD)   // 74
#define PROW 76                  // padded LDS row stride (multiple of 4 for float4)
#define NTHREADS 256

__global__ __launch_bounds__(NTHREADS)
void lcs_kernel(const float* __restrict__ x, const float* __restrict__ y,
                float* __restrict__ out) {
    // products: xx, yy, xy planes over the halo tile
    __shared__ float P[3][HALO_H][PROW];     // 3*42*76*4 = 38304 B
    __shared__ float Hs[HALO_H][TW];         // 42*64*4  = 10752 B  (reused per plane)

    const int tid = threadIdx.x;
    const int w0 = blockIdx.x * TW;
    const int h0 = blockIdx.y * TH;
    const int b  = blockIdx.z;

    // ---- Phase 0: channel-reduced products into LDS (zero outside image) ----
    for (int i = tid; i < HALO_H * HALO_W; i += NTHREADS) {
        const int r  = i / HALO_W;
        const int cc = i - r * HALO_W;
        const int gh = h0 + r  - KRAD;
        const int gw = w0 + cc - KRAD;
        float sxx = 0.f, syy = 0.f, sxy = 0.f;
        if ((unsigned)gh < (unsigned)NH && (unsigned)gw < (unsigned)NW) {
            const size_t chan = (size_t)NH * NW;
            size_t base = (size_t)b * NC * chan + (size_t)gh * NW + gw;
            #pragma unroll
            for (int c = 0; c < NC; ++c) {
                const float xv = x[base + (size_t)c * chan];
                const float yv = y[base + (size_t)c * chan];
                sxx += xv * xv;
                syy += yv * yv;
                sxy += xv * yv;
            }
        }
        P[0][r][cc] = sxx;
        P[1][r][cc] = syy;
        P[2][r][cc] = sxy;
    }
    __syncthreads();

    const int c     = tid & (TW - 1);     // 0..63
    const int rbase = (tid >> 6) * 8;     // 0,8,16,24  (8 output rows per thread)

    float acc[3][8];

    for (int p = 0; p < 3; ++p) {
        // ---- Phase H: horizontal 11-tap sums, 4 outputs per unit ----
        // Output col c needs halo cols c..c+10.
        for (int u = tid; u < HALO_H * (TW / 4); u += NTHREADS) {
            const int r  = u >> 4;           // / (TW/4)
            const int c4 = (u & 15) << 2;
            const float* row = &P[p][r][0];
            const float4 a0 = *(const float4*)(row + c4);
            const float4 a1 = *(const float4*)(row + c4 + 4);
            const float4 a2 = *(const float4*)(row + c4 + 8);
            const float4 a3 = *(const float4*)(row + c4 + 12);  // .z/.w may be pad, unused
            const float v0 = a0.x, v1 = a0.y, v2 = a0.z,  v3 = a0.w;
            const float v4 = a1.x, v5 = a1.y, v6 = a1.z,  v7 = a1.w;
            const float v8 = a2.x, v9 = a2.y, v10 = a2.z, v11 = a2.w;
            const float v12 = a3.x, v13 = a3.y;
            const float s0 = ((v0 + v1) + (v2 + v3)) + ((v4 + v5) + (v6 + v7))
                           + ((v8 + v9) + v10);
            const float s1 = s0 - v0 + v11;
            const float s2 = s1 - v1 + v12;
            const float s3 = s2 - v2 + v13;
            float4 o; o.x = s0; o.y = s1; o.z = s2; o.w = s3;
            *(float4*)(&Hs[r][c4]) = o;
        }
        __syncthreads();

        // ---- Phase V: vertical 11-tap running sum into registers ----
        {
            float s = 0.f;
            #pragma unroll
            for (int d = 0; d < KSZ; ++d) s += Hs[rbase + d][c];
            acc[p][0] = s;
            #pragma unroll
            for (int j = 1; j < 8; ++j) {
                s += Hs[rbase + j + (KSZ - 1)][c] - Hs[rbase + j - 1][c];
                acc[p][j] = s;
            }
        }
        __syncthreads();   // Hs reused by next plane
    }

    // ---- Finalize + coalesced store ----
    #pragma unroll
    for (int j = 0; j < 8; ++j) {
        const float xx = acc[0][j];
        const float yy = acc[1][j];
        const float xy = acc[2][j];
        const float denom = sqrtf(xx) * sqrtf(yy) + EPS;
        const size_t oidx = ((size_t)b * NH + (h0 + rbase + j)) * NW + (w0 + c);
        out[oidx] = xy / denom;
    }
}

extern "C" void kernel_launch(void* const* d_in, const int* in_sizes, int n_in,
                              void* d_out, int out_size, void* d_ws, size_t ws_size,
                              hipStream_t stream) {
    const float* x = (const float*)d_in[0];
    const float* y = (const float*)d_in[1];
    float* out = (float*)d_out;
    dim3 grid(NW / TW, NH / TH, NB);   // 16 x 32 x 8 = 4096 blocks
    lcs_kernel<<<grid, NTHREADS, 0, stream>>>(x, y, out);
}